// Round 7
// baseline (70.280 us; speedup 1.0000x reference)
//
#include <hip/hip_runtime.h>
#include <hip/hip_bf16.h>

// 4-qubit QNN, batch 1M — single fused kernel.
// out[b] = psi^T M psi, psi = prod_i [cos(x_i/2), sin(x_i/2)] (wire i = bit 3-i),
// M = Re(U^dag Z0 U). Per-qubit expansion c^2=(1+C)/2, cs=S/2, s^2=(1-C)/2
// (C=cos x, S=sin x)  =>  out = sum_{g in {1,C,S}^4} K[g] * prod basis.
// This round: (1) x-loads issued BEFORE the K-builder preamble (latency hides
// under it), (2) raw v_sin_f32/v_cos_f32 via __builtin_amdgcn_{sin,cos}f
// (input pre-scaled by 1/2pi, an inline constant), (3) K packed as float4[27]
// so the inner loop does 27 ds_read_b128 instead of 81 ds_read_b32.

#define BLOCK 256
#define VEC 4   // samples per thread
#define INV_2PI 0.15915494309189535f

__global__ __launch_bounds__(BLOCK) void qnn_fused_kernel(
    const float4* __restrict__ x, const float* __restrict__ w,
    float* __restrict__ out, int n) {

    __shared__ float Ur[16][17], Ui[16][17];
    __shared__ float Msh[256];
    __shared__ float4 Ks4[27];   // (k0,k1,k2,pad) per (d0,d1,d2)

    const int t = threadIdx.x;
    const int gid = blockIdx.x * BLOCK + t;
    const int stride = gridDim.x * BLOCK;
    const int step = stride * VEC;

    // ---- Prefetch first sample group BEFORE the preamble (hide HBM latency) ----
    int i0 = gid;
    float4 xv[VEC];
    #pragma unroll
    for (int v = 0; v < VEC; ++v) {
        const int ii = i0 + v * stride;
        xv[v] = x[(ii < n) ? ii : (n > 0 ? n - 1 : 0)];
    }

    // ---- Phase 1: U columns via register+shuffle sim (verified r1/r3/r6) ----
    {
        const int j = t >> 4;   // column (basis input)
        const int k = t & 15;   // row (amplitude index)
        float ur = (k == j) ? 1.0f : 0.0f;
        float ui = 0.0f;

        #pragma unroll
        for (int layer = 0; layer < 2; ++layer) {
            #pragma unroll
            for (int q = 0; q < 4; ++q) {
                const int bit = 3 - q;      // wire q acts on bit (3-q)
                const int str = 1 << bit;
                const int kb = (k >> bit) & 1;
                float c, s, pr, pi, nr, ni;
                // RX
                __sincosf(w[(layer * 4 + q) * 3 + 0] * 0.5f, &s, &c);
                pr = __shfl_xor(ur, str);
                pi = __shfl_xor(ui, str);
                nr = c * ur + s * pi;
                ni = c * ui - s * pr;
                ur = nr; ui = ni;
                // RY
                __sincosf(w[(layer * 4 + q) * 3 + 1] * 0.5f, &s, &c);
                pr = __shfl_xor(ur, str);
                pi = __shfl_xor(ui, str);
                {
                    const float sg = kb ? s : -s;
                    nr = c * ur + sg * pr;
                    ni = c * ui + sg * pi;
                }
                ur = nr; ui = ni;
                // RZ
                __sincosf(w[(layer * 4 + q) * 3 + 2] * 0.5f, &s, &c);
                {
                    const float sz = kb ? s : -s;
                    nr = c * ur - sz * ui;
                    ni = c * ui + sz * ur;
                }
                ur = nr; ui = ni;
            }
            // CNOT ring (0,1),(1,2),(2,3),(3,0)
            #pragma unroll
            for (int g = 0; g < 4; ++g) {
                const int cw = g;
                const int tw = (g + 1) & 3;
                const int bc = 3 - cw, bt = 3 - tw;
                const float pr = __shfl_xor(ur, 1 << bt);
                const float pi = __shfl_xor(ui, 1 << bt);
                const bool ctl = (k >> bc) & 1;
                ur = ctl ? pr : ur;
                ui = ctl ? pi : ui;
            }
        }
        Ur[k][j] = ur;
        Ui[k][j] = ui;
    }
    __syncthreads();

    // ---- Phase 2: M[a][b] = sum_k z_k Re(conj(U[k][a]) U[k][b]) ----
    {
        const int a = t >> 4, b = t & 15;
        float acc = 0.0f;
        #pragma unroll
        for (int kk = 0; kk < 16; ++kk) {
            const float v2 = Ur[kk][a] * Ur[kk][b] + Ui[kk][a] * Ui[kk][b];
            acc += (kk & 8) ? -v2 : v2;
        }
        Msh[t] = acc;
    }
    __syncthreads();

    // ---- Phase 3: 81 tensor coefficients, packed (k0,k1,k2,_) ----
    if (t < 81) {
        const int d0 = t / 27, d1 = (t / 9) % 3, d2 = (t / 3) % 3, d3 = t % 3;
        const int gd[4] = {d3, d2, d1, d0};  // digit per bit p
        float sum = 0.0f;
        #pragma unroll
        for (int m = 0; m < 16; ++m) {
            int a2 = 0, b2 = 0;
            float sign = 1.0f;
            #pragma unroll
            for (int p = 0; p < 4; ++p) {
                const int cp = (m >> p) & 1;
                if (gd[p] == 2) { a2 |= cp << p; b2 |= (1 - cp) << p; }
                else {
                    a2 |= cp << p; b2 |= cp << p;
                    if (gd[p] == 1 && cp) sign = -sign;
                }
            }
            sum += sign * Msh[a2 * 16 + b2];
        }
        ((float*)Ks4)[(t / 3) * 4 + (t % 3)] = sum * 0.0625f;
    }
    __syncthreads();

    // ---- Phase 4: stream samples; raw HW sin/cos; 27x ds_read_b128 ----
    for (; i0 < n;) {
        float C[VEC][4], S[VEC][4];
        #pragma unroll
        for (int v = 0; v < VEC; ++v) {
            const float r0 = xv[v].x * INV_2PI;
            const float r1 = xv[v].y * INV_2PI;
            const float r2 = xv[v].z * INV_2PI;
            const float r3 = xv[v].w * INV_2PI;
            S[v][0] = __builtin_amdgcn_sinf(r0); C[v][0] = __builtin_amdgcn_cosf(r0);
            S[v][1] = __builtin_amdgcn_sinf(r1); C[v][1] = __builtin_amdgcn_cosf(r1);
            S[v][2] = __builtin_amdgcn_sinf(r2); C[v][2] = __builtin_amdgcn_cosf(r2);
            S[v][3] = __builtin_amdgcn_sinf(r3); C[v][3] = __builtin_amdgcn_cosf(r3);
        }

        // prefetch next group (rare: only when grid doesn't cover n)
        const int inext = i0 + step;
        const bool more = inext < n;
        float4 xn[VEC];
        if (more) {
            #pragma unroll
            for (int v = 0; v < VEC; ++v) {
                const int ii = inext + v * stride;
                xn[v] = x[(ii < n) ? ii : (n - 1)];
            }
        }

        float r[VEC];
        #pragma unroll
        for (int d0 = 0; d0 < 3; ++d0) {
            float a1[VEC];
            #pragma unroll
            for (int d1 = 0; d1 < 3; ++d1) {
                float a2[VEC];
                #pragma unroll
                for (int d2 = 0; d2 < 3; ++d2) {
                    const float4 kf = Ks4[(d0 * 3 + d1) * 3 + d2];
                    #pragma unroll
                    for (int v = 0; v < VEC; ++v) {
                        const float tt = fmaf(kf.z, S[v][3], fmaf(kf.y, C[v][3], kf.x));
                        if (d2 == 0) a2[v] = tt;
                        else a2[v] = fmaf(tt, (d2 == 1) ? C[v][2] : S[v][2], a2[v]);
                    }
                }
                #pragma unroll
                for (int v = 0; v < VEC; ++v) {
                    if (d1 == 0) a1[v] = a2[v];
                    else a1[v] = fmaf(a2[v], (d1 == 1) ? C[v][1] : S[v][1], a1[v]);
                }
            }
            #pragma unroll
            for (int v = 0; v < VEC; ++v) {
                if (d0 == 0) r[v] = a1[v];
                else r[v] = fmaf(a1[v], (d0 == 1) ? C[v][0] : S[v][0], r[v]);
            }
        }

        #pragma unroll
        for (int v = 0; v < VEC; ++v) {
            const int ii = i0 + v * stride;
            if (ii < n) out[ii] = r[v];
        }

        i0 = inext;
        if (more) {
            #pragma unroll
            for (int v = 0; v < VEC; ++v) xv[v] = xn[v];
        }
    }
}

// ---------------- launch ----------------
extern "C" void kernel_launch(void* const* d_in, const int* in_sizes, int n_in,
                              void* d_out, int out_size, void* d_ws, size_t ws_size,
                              hipStream_t stream) {
    const float* x = (const float*)d_in[0];
    const float* w = (const float*)d_in[1];
    float* out = (float*)d_out;

    const int n = in_sizes[0] / 4;  // batch

    int grid = (n + BLOCK * VEC - 1) / (BLOCK * VEC);  // 1024 for n = 1M
    if (grid < 1) grid = 1;
    if (grid > 4096) grid = 4096;

    qnn_fused_kernel<<<grid, BLOCK, 0, stream>>>((const float4*)x, w, out, n);
}